// Round 1
// baseline (174.617 us; speedup 1.0000x reference)
//
#include <hip/hip_runtime.h>
#include <hip/hip_bf16.h>
#include <hip/hip_cooperative_groups.h>

// Problem constants
#define CC   256   // channels
#define HWs  256   // h*w
#define TDs  768   // num_heads * head_features
#define QO   2304  // 3 * TD

namespace cg = cooperative_groups;

typedef __attribute__((ext_vector_type(8))) short short8;   // 8 bf16 (4 VGPRs)
typedef __attribute__((ext_vector_type(4))) float f32x4;    // MFMA accum

__device__ __forceinline__ short f2bf(float f) {
    __hip_bfloat16 h = __float2bfloat16(f);
    return *reinterpret_cast<short*>(&h);
}

// ---------------------------------------------------------------------------
// Single cooperative kernel, grid 256 x 256 threads (1 block/CU guaranteed
// co-resident: 64 KB LDS, modest VGPR). Three phases, two grid syncs:
//   P1: qkv = wqkv @ x          (288 64x64 tiles; 32 blocks do 2 tiles)
//   P2: Taylor-moment attention (384 groups of 4 slices; 128 blocks do 2)
//   P3: out-proj + residual + LayerNorm fused (16 blocks: b x 32-c-rows,
//       full p=256 per block so LN reduction is block-local; K=768 streamed
//       in 12 chunks of 64 with on-the-fly wout fp32->bf16 conversion)
// Eliminated vs 4-kernel version: part buffer (8.4 MB round-trip), woutb
// buffer + its conversion pass, 3 kernel boundaries.
// ---------------------------------------------------------------------------
__global__ __launch_bounds__(256)
void k_fused(const float* __restrict__ x, const float* __restrict__ wqkv,
             const float* __restrict__ wout, float* __restrict__ qkv,
             short* __restrict__ aoT, float* __restrict__ out) {
    __shared__ __align__(16) short sA[64 * 256];   // 32 KB
    __shared__ __align__(16) short sB[64 * 256];   // 32 KB   (total = 64 KB)

    const int tid = threadIdx.x;
    const int bk = blockIdx.x;
    const int w = tid >> 6, lane = tid & 63;
    const int quad = lane >> 4, l15 = lane & 15;

    // ================= Phase 1: qkv GEMM ================================
    for (int t = bk; t < 288; t += 256) {
        __syncthreads();                     // protect LDS reuse across tiles
        const int b  = t / 144;
        const int r2 = t - b * 144;
        const int p0 = (r2 / 36) * 64;
        const int o0 = (r2 % 36) * 64;
        const float* xb = x + b * CC * HWs;

        // stage A: wqkv rows o0..o0+63, all 256 c
        {
            const float* src = wqkv + o0 * CC;
#pragma unroll
            for (int i = 0; i < 16; ++i) {
                const int flat = i * 1024 + tid * 4;
                float4 v = *(const float4*)(src + flat);
                const int o = flat >> 8, c = flat & 255;
                const int addr = o * 256 + (((c >> 3) ^ (o & 31)) << 3) + (c & 7);
                short4 s4 = make_short4(f2bf(v.x), f2bf(v.y), f2bf(v.z), f2bf(v.w));
                *(short4*)&sA[addr] = s4;
            }
        }
        // stage B transposed: x[c][p-tile] -> sB[p][c]
        {
            const int c_in = tid >> 4, p4 = (tid & 15) * 4;
#pragma unroll
            for (int i = 0; i < 16; ++i) {
                const int c = i * 16 + c_in;
                float4 v = *(const float4*)(xb + c * HWs + p0 + p4);
                float vv[4] = {v.x, v.y, v.z, v.w};
#pragma unroll
                for (int j = 0; j < 4; ++j) {
                    const int p = p4 + j;
                    sB[p * 256 + (((c >> 3) ^ (p & 31)) << 3) + (c & 7)] = f2bf(vv[j]);
                }
            }
        }
        __syncthreads();

        const int oo = (w & 1) * 32, pp = (w >> 1) * 32;
        f32x4 acc[2][2] = {};
#pragma unroll
        for (int step = 0; step < 8; ++step) {
            const int chunk = step * 4 + quad;
            const int ra0 = oo + l15, ra1 = oo + 16 + l15;
            const int rb0 = pp + l15, rb1 = pp + 16 + l15;
            short8 a0 = *(const short8*)&sA[ra0 * 256 + ((chunk ^ (ra0 & 31)) << 3)];
            short8 a1 = *(const short8*)&sA[ra1 * 256 + ((chunk ^ (ra1 & 31)) << 3)];
            short8 b0 = *(const short8*)&sB[rb0 * 256 + ((chunk ^ (rb0 & 31)) << 3)];
            short8 b1 = *(const short8*)&sB[rb1 * 256 + ((chunk ^ (rb1 & 31)) << 3)];
            acc[0][0] = __builtin_amdgcn_mfma_f32_16x16x32_bf16(a0, b0, acc[0][0], 0, 0, 0);
            acc[0][1] = __builtin_amdgcn_mfma_f32_16x16x32_bf16(a0, b1, acc[0][1], 0, 0, 0);
            acc[1][0] = __builtin_amdgcn_mfma_f32_16x16x32_bf16(a1, b0, acc[1][0], 0, 0, 0);
            acc[1][1] = __builtin_amdgcn_mfma_f32_16x16x32_bf16(a1, b1, acc[1][1], 0, 0, 0);
        }

        float* outp = qkv + b * QO * HWs;
#pragma unroll
        for (int ti = 0; ti < 2; ++ti)
#pragma unroll
            for (int tj = 0; tj < 2; ++tj)
#pragma unroll
                for (int r = 0; r < 4; ++r) {
                    const int o = o0 + oo + ti * 16 + quad * 4 + r;
                    const int p = p0 + pp + tj * 16 + l15;
                    outp[o * HWs + p] = acc[ti][tj][r];
                }
    }
    cg::this_grid().sync();

    // ================= Phase 2: Taylor attention ========================
    {
        float* sOut = (float*)sA;            // [256][5] alias, 5 KB
        for (int g = bk; g < 384; g += 256) {
            const int s = g * 4 + w;         // group never straddles b (4|768)
            const int b2 = (s >= TDs) ? 1 : 0;
            const int o2 = s - b2 * TDs;
            const float* base = qkv + b2 * QO * HWs;
            const float* qp = base + o2 * HWs;
            const float* kp = base + (TDs + o2) * HWs;
            const float* vp = base + (2 * TDs + o2) * HWs;

            float A[8] = {}, B[8] = {};
#pragma unroll
            for (int r = 0; r < 4; ++r) {
                const int j = lane + 64 * r;
                const float k = kp[j], v = vp[j];
                float p = 1.f;
#pragma unroll
                for (int m = 0; m < 8; ++m) {
                    A[m] += p * v;
                    B[m] += p;
                    p *= k;
                }
            }
#pragma unroll
            for (int off = 1; off < 64; off <<= 1) {
#pragma unroll
                for (int m = 0; m < 8; ++m) {
                    A[m] += __shfl_xor(A[m], off, 64);
                    B[m] += __shfl_xor(B[m], off, 64);
                }
            }
            const float inv_fact[8] = {1.f, 1.f, 0.5f, 1.f / 6.f, 1.f / 24.f,
                                       1.f / 120.f, 1.f / 720.f, 1.f / 5040.f};
#pragma unroll
            for (int m = 0; m < 8; ++m) { A[m] *= inv_fact[m]; B[m] *= inv_fact[m]; }

#pragma unroll
            for (int r = 0; r < 4; ++r) {
                const int i = lane + 64 * r;
                const float u = qp[i] * 0.125f;
                float N = A[7], D = B[7];
#pragma unroll
                for (int m = 6; m >= 0; --m) {
                    N = fmaf(N, u, A[m]);
                    D = fmaf(D, u, B[m]);
                }
                sOut[i * 5 + w] = N / D;
            }
            __syncthreads();
            const int o2g = g * 4 - b2 * TDs;
            short4 sv = make_short4(f2bf(sOut[tid * 5 + 0]), f2bf(sOut[tid * 5 + 1]),
                                    f2bf(sOut[tid * 5 + 2]), f2bf(sOut[tid * 5 + 3]));
            *(short4*)&aoT[(b2 * HWs + tid) * TDs + o2g] = sv;
            __syncthreads();                 // protect sOut reuse by next group
        }
    }
    cg::this_grid().sync();

    // ================= Phase 3: proj + residual + LayerNorm =============
    if (bk >= 16) return;
    {
        const int b3 = bk >> 3;
        const int c0 = (bk & 7) * 32;
        float* red_s = (float*)&sA[8192];    // bytes 16384.. : disjoint from
        float* red_q = red_s + 128;          // phase-3 A-tile (bytes 0..4095)

        f32x4 acc[2][4] = {};
        for (int kc = 0; kc < 12; ++kc) {
            __syncthreads();                 // prev chunk's frag reads done
            {   // stage A: wout[c0..c0+31][kc*64 ..+64) fp32 -> bf16, swizzled
                const int row = tid >> 3, col = (tid & 7) * 8;
                const float* srcp = wout + (c0 + row) * TDs + kc * 64 + col;
                float4 v0 = *(const float4*)(srcp);
                float4 v1 = *(const float4*)(srcp + 4);
                short8 s8;
                s8[0] = f2bf(v0.x); s8[1] = f2bf(v0.y);
                s8[2] = f2bf(v0.z); s8[3] = f2bf(v0.w);
                s8[4] = f2bf(v1.x); s8[5] = f2bf(v1.y);
                s8[6] = f2bf(v1.z); s8[7] = f2bf(v1.w);
                const int chunk = col >> 3;
                *(short8*)&sA[row * 64 + ((chunk ^ (row & 7)) << 3)] = s8;
            }
#pragma unroll
            for (int i = 0; i < 8; ++i) {    // stage B: aoT[b3][0..255][chunk]
                const int flat = i * 2048 + tid * 8;
                const int row = flat >> 6, col = flat & 63;
                short8 vv = *(const short8*)&aoT[(b3 * HWs + row) * TDs + kc * 64 + col];
                const int chunk = col >> 3;
                *(short8*)&sB[row * 64 + ((chunk ^ (row & 7)) << 3)] = vv;
            }
            __syncthreads();
#pragma unroll
            for (int ks = 0; ks < 2; ++ks) {
                const int ck = ks * 4 + quad;
                const int ra0 = l15, ra1 = 16 + l15;
                short8 a0 = *(const short8*)&sA[ra0 * 64 + ((ck ^ (ra0 & 7)) << 3)];
                short8 a1 = *(const short8*)&sA[ra1 * 64 + ((ck ^ (ra1 & 7)) << 3)];
#pragma unroll
                for (int tj = 0; tj < 4; ++tj) {
                    const int rb = w * 64 + tj * 16 + l15;
                    short8 bb = *(const short8*)&sB[rb * 64 + ((ck ^ (rb & 7)) << 3)];
                    acc[0][tj] = __builtin_amdgcn_mfma_f32_16x16x32_bf16(a0, bb, acc[0][tj], 0, 0, 0);
                    acc[1][tj] = __builtin_amdgcn_mfma_f32_16x16x32_bf16(a1, bb, acc[1][tj], 0, 0, 0);
                }
            }
        }

        // epilogue: y = proj + x, then LayerNorm over p per c-row
        float y[2][4][4];                    // [ti][tj][r]
        float ps[2][4], pq2[2][4];
#pragma unroll
        for (int ti = 0; ti < 2; ++ti)
#pragma unroll
            for (int r = 0; r < 4; ++r) {
                const int c = ti * 16 + quad * 4 + r;
                const float* xrow = x + ((b3 * CC) + c0 + c) * HWs + w * 64 + l15;
                float s = 0.f, q = 0.f;
#pragma unroll
                for (int tj = 0; tj < 4; ++tj) {
                    const float yy = acc[ti][tj][r] + xrow[tj * 16];
                    y[ti][tj][r] = yy;
                    s += yy;
                    q += yy * yy;
                }
                ps[ti][r] = s; pq2[ti][r] = q;
            }
#pragma unroll
        for (int off = 1; off < 16; off <<= 1) {
#pragma unroll
            for (int ti = 0; ti < 2; ++ti)
#pragma unroll
                for (int r = 0; r < 4; ++r) {
                    ps[ti][r]  += __shfl_xor(ps[ti][r], off, 64);
                    pq2[ti][r] += __shfl_xor(pq2[ti][r], off, 64);
                }
        }
        if (l15 == 0) {
#pragma unroll
            for (int ti = 0; ti < 2; ++ti)
#pragma unroll
                for (int r = 0; r < 4; ++r) {
                    const int c = ti * 16 + quad * 4 + r;
                    red_s[c * 4 + w] = ps[ti][r];
                    red_q[c * 4 + w] = pq2[ti][r];
                }
        }
        __syncthreads();
#pragma unroll
        for (int ti = 0; ti < 2; ++ti)
#pragma unroll
            for (int r = 0; r < 4; ++r) {
                const int c = ti * 16 + quad * 4 + r;
                const float ts = (red_s[c * 4 + 0] + red_s[c * 4 + 1]) +
                                 (red_s[c * 4 + 2] + red_s[c * 4 + 3]);
                const float tq = (red_q[c * 4 + 0] + red_q[c * 4 + 1]) +
                                 (red_q[c * 4 + 2] + red_q[c * 4 + 3]);
                const float mu  = ts * (1.f / 256.f);
                const float var = tq * (1.f / 256.f) - mu * mu;
                const float inv = rsqrtf(var + 1e-5f);
                float* orow = out + ((b3 * CC) + c0 + c) * HWs + w * 64 + l15;
#pragma unroll
                for (int tj = 0; tj < 4; ++tj)
                    orow[tj * 16] = (y[ti][tj][r] - mu) * inv;
            }
    }
}

// ---------------------------------------------------------------------------
extern "C" void kernel_launch(void* const* d_in, const int* in_sizes, int n_in,
                              void* d_out, int out_size, void* d_ws, size_t ws_size,
                              hipStream_t stream) {
    const float* x    = (const float*)d_in[0];
    const float* wqkv = (const float*)d_in[1];
    const float* wout = (const float*)d_in[2];
    // d_in[3] = b_out: zeros, and per-row constants cancel in LayerNorm.

    char* ws = (char*)d_ws;
    float* qkv = (float*)(ws);               // 2*2304*256 f32 = 4,718,592 B
    short* aoT = (short*)(ws + 4718592);     // 2*256*768 bf16 =  786,432 B
    float* out = (float*)d_out;

    void* args[] = {(void*)&x, (void*)&wqkv, (void*)&wout,
                    (void*)&qkv, (void*)&aoT, (void*)&out};
    hipLaunchCooperativeKernel((const void*)k_fused, dim3(256), dim3(256),
                               args, 0, stream);
}

// Round 2
// 81.054 us; speedup vs baseline: 2.1543x; 2.1543x over previous
//
#include <hip/hip_runtime.h>
#include <hip/hip_bf16.h>

// Problem constants
#define CC   256   // channels
#define HWs  256   // h*w
#define TDs  768   // num_heads * head_features
#define QO   2304  // 3 * TD

typedef __attribute__((ext_vector_type(8))) short short8;   // 8 bf16 (4 VGPRs)
typedef __attribute__((ext_vector_type(4))) float f32x4;    // MFMA accum

__device__ __forceinline__ short f2bf(float f) {
    __hip_bfloat16 h = __float2bfloat16(f);
    return *reinterpret_cast<short*>(&h);
}

// ---------------------------------------------------------------------------
// K1: qkv[b][o][p] = sum_c wqkv[o][c] * x[b][c][p]  via bf16 MFMA 16x16x32.
// (unchanged from the proven 80-81us version)
// ---------------------------------------------------------------------------
__global__ __launch_bounds__(256)
void k_qkv(const float* __restrict__ wqkv, const float* __restrict__ x,
           float* __restrict__ qkv) {
    __shared__ __align__(16) short sA[64 * 256];
    __shared__ __align__(16) short sB[64 * 256];
    const int tid = threadIdx.x;
    const int o0 = blockIdx.x * 64, p0 = blockIdx.y * 64, b = blockIdx.z;
    const float* xb = x + b * CC * HWs;

    // --- stage A: wqkv rows o0..o0+63, all 256 c (contiguous 16K floats)
    {
        const float* src = wqkv + o0 * CC;
#pragma unroll
        for (int i = 0; i < 16; ++i) {
            const int flat = i * 1024 + tid * 4;     // element index
            float4 v = *(const float4*)(src + flat);
            const int o = flat >> 8, c = flat & 255;
            const int addr = o * 256 + (((c >> 3) ^ (o & 31)) << 3) + (c & 7);
            short4 s = make_short4(f2bf(v.x), f2bf(v.y), f2bf(v.z), f2bf(v.w));
            *(short4*)&sA[addr] = s;
        }
    }
    // --- stage B transposed: x[c][p-tile] -> sB[p][c]
    {
        const int c_in = tid >> 4, p4 = (tid & 15) * 4;
#pragma unroll
        for (int i = 0; i < 16; ++i) {
            const int c = i * 16 + c_in;
            float4 v = *(const float4*)(xb + c * HWs + p0 + p4);
            float vv[4] = {v.x, v.y, v.z, v.w};
#pragma unroll
            for (int j = 0; j < 4; ++j) {
                const int p = p4 + j;
                sB[p * 256 + (((c >> 3) ^ (p & 31)) << 3) + (c & 7)] = f2bf(vv[j]);
            }
        }
    }
    __syncthreads();

    const int w = tid >> 6, lane = tid & 63;
    const int quad = lane >> 4, l15 = lane & 15;
    const int oo = (w & 1) * 32, pp = (w >> 1) * 32;
    f32x4 acc[2][2] = {};

#pragma unroll
    for (int step = 0; step < 8; ++step) {
        const int chunk = step * 4 + quad;
        const int ra0 = oo + l15, ra1 = oo + 16 + l15;
        const int rb0 = pp + l15, rb1 = pp + 16 + l15;
        short8 a0 = *(const short8*)&sA[ra0 * 256 + ((chunk ^ (ra0 & 31)) << 3)];
        short8 a1 = *(const short8*)&sA[ra1 * 256 + ((chunk ^ (ra1 & 31)) << 3)];
        short8 b0 = *(const short8*)&sB[rb0 * 256 + ((chunk ^ (rb0 & 31)) << 3)];
        short8 b1 = *(const short8*)&sB[rb1 * 256 + ((chunk ^ (rb1 & 31)) << 3)];
        acc[0][0] = __builtin_amdgcn_mfma_f32_16x16x32_bf16(a0, b0, acc[0][0], 0, 0, 0);
        acc[0][1] = __builtin_amdgcn_mfma_f32_16x16x32_bf16(a0, b1, acc[0][1], 0, 0, 0);
        acc[1][0] = __builtin_amdgcn_mfma_f32_16x16x32_bf16(a1, b0, acc[1][0], 0, 0, 0);
        acc[1][1] = __builtin_amdgcn_mfma_f32_16x16x32_bf16(a1, b1, acc[1][1], 0, 0, 0);
    }

    float* outp = qkv + b * QO * HWs;
#pragma unroll
    for (int ti = 0; ti < 2; ++ti)
#pragma unroll
        for (int tj = 0; tj < 2; ++tj)
#pragma unroll
            for (int r = 0; r < 4; ++r) {
                const int o = o0 + oo + ti * 16 + quad * 4 + r;
                const int p = p0 + pp + tj * 16 + l15;
                outp[o * HWs + p] = acc[ti][tj][r];
            }
}

// ---------------------------------------------------------------------------
// K2: attention via exact Taylor moments, one wave/slice.
// Change vs proven version: float4 vectorized q/k/v loads (3 VMEM ops
// instead of 12 scalar dwords per thread; identical math and bytes).
// Blocks 384..447 convert wout -> bf16. grid 448.
// ---------------------------------------------------------------------------
__global__ __launch_bounds__(256)
void k_attn(const float* __restrict__ qkv, const float* __restrict__ wout,
            short* __restrict__ aoT, short* __restrict__ wout_bf) {
    const int bk = blockIdx.x;
    if (bk >= 384) {  // wout fp32 -> bf16 convert role (196608 elems)
        const int bk2 = bk - 384;
#pragma unroll
        for (int i = 0; i < 3; ++i) {
            const int f4 = bk2 * 256 + threadIdx.x + i * 16384;
            float4 v = *(const float4*)(wout + f4 * 4);
            short4 s = make_short4(f2bf(v.x), f2bf(v.y), f2bf(v.z), f2bf(v.w));
            *(short4*)&wout_bf[f4 * 4] = s;
        }
        return;
    }

    __shared__ float sOut[256][5];
    const int lane = threadIdx.x & 63;
    const int w = threadIdx.x >> 6;
    const int s = bk * 4 + w;                 // 0..1535 (4|768: no b straddle)
    const int b = s / TDs, o2 = s - b * TDs;
    const float* base = qkv + b * QO * HWs;
    const float* qp = base + o2 * HWs;
    const float* kp = base + (TDs + o2) * HWs;
    const float* vp = base + (2 * TDs + o2) * HWs;

    float A[8] = {}, B[8] = {};
    {
        float4 k4 = *(const float4*)(kp + lane * 4);
        float4 v4 = *(const float4*)(vp + lane * 4);
        const float kk[4] = {k4.x, k4.y, k4.z, k4.w};
        const float vv[4] = {v4.x, v4.y, v4.z, v4.w};
#pragma unroll
        for (int e = 0; e < 4; ++e) {
            const float k = kk[e], v = vv[e];
            float p = 1.f;
#pragma unroll
            for (int m = 0; m < 8; ++m) {
                A[m] += p * v;
                B[m] += p;
                p *= k;
            }
        }
    }
#pragma unroll
    for (int off = 1; off < 64; off <<= 1) {
#pragma unroll
        for (int m = 0; m < 8; ++m) {
            A[m] += __shfl_xor(A[m], off, 64);
            B[m] += __shfl_xor(B[m], off, 64);
        }
    }
    const float inv_fact[8] = {1.f, 1.f, 0.5f, 1.f / 6.f, 1.f / 24.f,
                               1.f / 120.f, 1.f / 720.f, 1.f / 5040.f};
#pragma unroll
    for (int m = 0; m < 8; ++m) { A[m] *= inv_fact[m]; B[m] *= inv_fact[m]; }

    {
        float4 q4 = *(const float4*)(qp + lane * 4);
        const float qq[4] = {q4.x, q4.y, q4.z, q4.w};
#pragma unroll
        for (int e = 0; e < 4; ++e) {
            const float u = qq[e] * 0.125f;
            float N = A[7], D = B[7];
#pragma unroll
            for (int m = 6; m >= 0; --m) {
                N = fmaf(N, u, A[m]);
                D = fmaf(D, u, B[m]);
            }
            sOut[lane * 4 + e][w] = N / D;
        }
    }
    __syncthreads();
    const int t = threadIdx.x;
    const int o2g = bk * 4 - b * TDs;         // block's o2 base (mult of 4)
    short4 sv = make_short4(f2bf(sOut[t][0]), f2bf(sOut[t][1]),
                            f2bf(sOut[t][2]), f2bf(sOut[t][3]));
    *(short4*)&aoT[(b * HWs + t) * TDs + o2g] = sv;
}

// ---------------------------------------------------------------------------
// K3: split-K output projection via bf16 MFMA (unchanged, proven).
// part[z][c][p] = sum_{k in slice} wout[c][k]*ao[k][p], z=b*8+ks, Kslice=96.
// ---------------------------------------------------------------------------
__global__ __launch_bounds__(256)
void k_proj(const short* __restrict__ wout_bf, const short* __restrict__ aoT,
            float* __restrict__ part) {
    __shared__ __align__(16) short sA[64 * 128];
    __shared__ __align__(16) short sB[64 * 128];
    const int tid = threadIdx.x;
    const int c0 = blockIdx.x * 64, p0 = blockIdx.y * 64;
    const int z = blockIdx.z, b = z >> 3, ks = z & 7;
    const int k0 = ks * 96;

#pragma unroll
    for (int i = 0; i < 6; ++i) {               // 1536 short4 per tensor
        const int idx = i * 256 + tid;
        const int row = idx / 24, col4 = idx - row * 24;
        const int lds = row * 128 + ((((col4 >> 1) ^ (row & 15)) << 3)) + ((col4 & 1) << 2);
        short4 a = *(const short4*)&wout_bf[(c0 + row) * TDs + k0 + col4 * 4];
        *(short4*)&sA[lds] = a;
        short4 bb = *(const short4*)&aoT[(b * HWs + p0 + row) * TDs + k0 + col4 * 4];
        *(short4*)&sB[lds] = bb;
    }
    __syncthreads();

    const int w = tid >> 6, lane = tid & 63;
    const int quad = lane >> 4, l15 = lane & 15;
    const int cc = (w & 1) * 32, pp = (w >> 1) * 32;
    f32x4 acc[2][2] = {};

#pragma unroll
    for (int step = 0; step < 3; ++step) {
        const int chunk = step * 4 + quad;
        const int ra0 = cc + l15, ra1 = cc + 16 + l15;
        const int rb0 = pp + l15, rb1 = pp + 16 + l15;
        short8 a0 = *(const short8*)&sA[ra0 * 128 + ((chunk ^ (ra0 & 15)) << 3)];
        short8 a1 = *(const short8*)&sA[ra1 * 128 + ((chunk ^ (ra1 & 15)) << 3)];
        short8 b0 = *(const short8*)&sB[rb0 * 128 + ((chunk ^ (rb0 & 15)) << 3)];
        short8 b1 = *(const short8*)&sB[rb1 * 128 + ((chunk ^ (rb1 & 15)) << 3)];
        acc[0][0] = __builtin_amdgcn_mfma_f32_16x16x32_bf16(a0, b0, acc[0][0], 0, 0, 0);
        acc[0][1] = __builtin_amdgcn_mfma_f32_16x16x32_bf16(a0, b1, acc[0][1], 0, 0, 0);
        acc[1][0] = __builtin_amdgcn_mfma_f32_16x16x32_bf16(a1, b0, acc[1][0], 0, 0, 0);
        acc[1][1] = __builtin_amdgcn_mfma_f32_16x16x32_bf16(a1, b1, acc[1][1], 0, 0, 0);
    }

    float* op = part + z * (CC * HWs);
#pragma unroll
    for (int ti = 0; ti < 2; ++ti)
#pragma unroll
        for (int tj = 0; tj < 2; ++tj)
#pragma unroll
            for (int r = 0; r < 4; ++r) {
                const int c = c0 + cc + ti * 16 + quad * 4 + r;
                const int p = p0 + pp + tj * 16 + l15;
                op[c * HWs + p] = acc[ti][tj][r];
            }
}

// ---------------------------------------------------------------------------
// K4: y = x + sum_ks part ; LayerNorm over p per (b,c); write out.
// Rewritten: one 64-thread wave per (b,c) row, float4 loads (4 p per lane),
// pure shfl_xor reduction — no LDS, no __syncthreads, 4x fewer VMEM ops.
// grid 512 x 64.
// ---------------------------------------------------------------------------
__global__ __launch_bounds__(64)
void k_ln(const float* __restrict__ x, const float* __restrict__ part,
          float* __restrict__ out) {
    const int lane = threadIdx.x;
    const int bc = blockIdx.x;         // b*256 + c
    const int b = bc >> 8, c = bc & 255;

    float4 y = *(const float4*)(x + bc * HWs + lane * 4);
#pragma unroll
    for (int ks = 0; ks < 8; ++ks) {
        float4 pv = *(const float4*)(part + (((b * 8 + ks) * CC + c) * HWs) + lane * 4);
        y.x += pv.x; y.y += pv.y; y.z += pv.z; y.w += pv.w;
    }

    float s  = (y.x + y.y) + (y.z + y.w);
    float ss = (y.x * y.x + y.y * y.y) + (y.z * y.z + y.w * y.w);
#pragma unroll
    for (int off = 1; off < 64; off <<= 1) {
        s  += __shfl_xor(s, off, 64);
        ss += __shfl_xor(ss, off, 64);
    }
    const float mu  = s * (1.f / 256.f);
    const float var = ss * (1.f / 256.f) - mu * mu;
    const float inv = rsqrtf(var + 1e-5f);
    float4 o;
    o.x = (y.x - mu) * inv;
    o.y = (y.y - mu) * inv;
    o.z = (y.z - mu) * inv;
    o.w = (y.w - mu) * inv;
    *(float4*)(out + bc * HWs + lane * 4) = o;
}

// ---------------------------------------------------------------------------
extern "C" void kernel_launch(void* const* d_in, const int* in_sizes, int n_in,
                              void* d_out, int out_size, void* d_ws, size_t ws_size,
                              hipStream_t stream) {
    const float* x    = (const float*)d_in[0];
    const float* wqkv = (const float*)d_in[1];
    const float* wout = (const float*)d_in[2];
    // d_in[3] = b_out: zeros, and per-row constants cancel in LayerNorm.

    char* ws = (char*)d_ws;
    float* qkv    = (float*)(ws);                    // 2*2304*256 f32 = 4,718,592 B
    short* aoT    = (short*)(ws + 4718592);          // 2*256*768 bf16 =  786,432 B
    short* woutb  = (short*)(ws + 5505024);          // 256*768  bf16 =  393,216 B
    float* part   = (float*)(ws + 5898240);          // 16*256*256 f32 = 4,194,304 B
    float* out    = (float*)d_out;

    k_qkv <<<dim3(36, 4, 2), 256, 0, stream>>>(wqkv, x, qkv);
    k_attn<<<dim3(448),      256, 0, stream>>>(qkv, wout, aoT, woutb);
    k_proj<<<dim3(4, 4, 16), 256, 0, stream>>>(woutb, aoT, part);
    k_ln  <<<dim3(512),       64, 0, stream>>>(x, part, out);
}

// Round 3
// 80.150 us; speedup vs baseline: 2.1786x; 1.0113x over previous
//
#include <hip/hip_runtime.h>
#include <hip/hip_bf16.h>

// Problem constants
#define CC   256   // channels
#define HWs  256   // h*w
#define TDs  768   // num_heads * head_features
#define QO   2304  // 3 * TD

typedef __attribute__((ext_vector_type(8))) short short8;   // 8 bf16 (4 VGPRs)
typedef __attribute__((ext_vector_type(4))) float f32x4;    // MFMA accum

__device__ __forceinline__ short f2bf(float f) {
    __hip_bfloat16 h = __float2bfloat16(f);
    return *reinterpret_cast<short*>(&h);
}

// ---------------------------------------------------------------------------
// K1: qkv[b][o][p] = sum_c wqkv[o][c] * x[b][c][p]  via bf16 MFMA 16x16x32.
// MFMA core identical to the proven version. New: (a) B-stage uses a 4x4
// register transpose -> 16 ds_write_b64 per thread instead of 64 scalar
// ds_write_b16; (b) blocks bx>=36 convert wout->bf16 (moved out of k_attn).
// grid (40, 4, 2), 256 threads.
// ---------------------------------------------------------------------------
__global__ __launch_bounds__(256)
void k_qkv(const float* __restrict__ wqkv, const float* __restrict__ x,
           float* __restrict__ qkv, const float* __restrict__ wout,
           short* __restrict__ wout_bf) {
    const int tid = threadIdx.x;
    if (blockIdx.x >= 36) {   // converter role: 32 blocks, 49152 float4 total
        const int cb = (blockIdx.x - 36) * 8 + blockIdx.y * 2 + blockIdx.z;
#pragma unroll
        for (int i = 0; i < 6; ++i) {
            const int f4 = cb * 1536 + i * 256 + tid;
            float4 v = *(const float4*)(wout + f4 * 4);
            short4 s = make_short4(f2bf(v.x), f2bf(v.y), f2bf(v.z), f2bf(v.w));
            *(short4*)&wout_bf[f4 * 4] = s;
        }
        return;
    }

    __shared__ __align__(16) short sA[64 * 256];
    __shared__ __align__(16) short sB[64 * 256];
    const int o0 = blockIdx.x * 64, p0 = blockIdx.y * 64, b = blockIdx.z;
    const float* xb = x + b * CC * HWs;

    // --- stage A: wqkv rows o0..o0+63, all 256 c (contiguous 16K floats)
    {
        const float* src = wqkv + o0 * CC;
#pragma unroll
        for (int i = 0; i < 16; ++i) {
            const int flat = i * 1024 + tid * 4;     // element index
            float4 v = *(const float4*)(src + flat);
            const int o = flat >> 8, c = flat & 255;
            const int addr = o * 256 + (((c >> 3) ^ (o & 31)) << 3) + (c & 7);
            short4 s = make_short4(f2bf(v.x), f2bf(v.y), f2bf(v.z), f2bf(v.w));
            *(short4*)&sA[addr] = s;
        }
    }
    // --- stage B transposed via 4x4 register transpose: x[c][p] -> sB[p][c]
    {
#pragma unroll
        for (int j = 0; j < 4; ++j) {
            const int bi = j * 256 + tid;            // 0..1023 (16p4 x 64c4)
            const int p4 = (bi & 15) * 4;
            const int c4 = (bi >> 4) * 4;
            float4 r0 = *(const float4*)(xb + (c4 + 0) * HWs + p0 + p4);
            float4 r1 = *(const float4*)(xb + (c4 + 1) * HWs + p0 + p4);
            float4 r2 = *(const float4*)(xb + (c4 + 2) * HWs + p0 + p4);
            float4 r3 = *(const float4*)(xb + (c4 + 3) * HWs + p0 + p4);
            short4 s0 = make_short4(f2bf(r0.x), f2bf(r1.x), f2bf(r2.x), f2bf(r3.x));
            short4 s1 = make_short4(f2bf(r0.y), f2bf(r1.y), f2bf(r2.y), f2bf(r3.y));
            short4 s2 = make_short4(f2bf(r0.z), f2bf(r1.z), f2bf(r2.z), f2bf(r3.z));
            short4 s3 = make_short4(f2bf(r0.w), f2bf(r1.w), f2bf(r2.w), f2bf(r3.w));
            const int ch = c4 >> 3, cl = c4 & 7;
            *(short4*)&sB[(p4 + 0) * 256 + ((ch ^ ((p4 + 0) & 31)) << 3) + cl] = s0;
            *(short4*)&sB[(p4 + 1) * 256 + ((ch ^ ((p4 + 1) & 31)) << 3) + cl] = s1;
            *(short4*)&sB[(p4 + 2) * 256 + ((ch ^ ((p4 + 2) & 31)) << 3) + cl] = s2;
            *(short4*)&sB[(p4 + 3) * 256 + ((ch ^ ((p4 + 3) & 31)) << 3) + cl] = s3;
        }
    }
    __syncthreads();

    const int w = tid >> 6, lane = tid & 63;
    const int quad = lane >> 4, l15 = lane & 15;
    const int oo = (w & 1) * 32, pp = (w >> 1) * 32;
    f32x4 acc[2][2] = {};

#pragma unroll
    for (int step = 0; step < 8; ++step) {
        const int chunk = step * 4 + quad;
        const int ra0 = oo + l15, ra1 = oo + 16 + l15;
        const int rb0 = pp + l15, rb1 = pp + 16 + l15;
        short8 a0 = *(const short8*)&sA[ra0 * 256 + ((chunk ^ (ra0 & 31)) << 3)];
        short8 a1 = *(const short8*)&sA[ra1 * 256 + ((chunk ^ (ra1 & 31)) << 3)];
        short8 b0 = *(const short8*)&sB[rb0 * 256 + ((chunk ^ (rb0 & 31)) << 3)];
        short8 b1 = *(const short8*)&sB[rb1 * 256 + ((chunk ^ (rb1 & 31)) << 3)];
        acc[0][0] = __builtin_amdgcn_mfma_f32_16x16x32_bf16(a0, b0, acc[0][0], 0, 0, 0);
        acc[0][1] = __builtin_amdgcn_mfma_f32_16x16x32_bf16(a0, b1, acc[0][1], 0, 0, 0);
        acc[1][0] = __builtin_amdgcn_mfma_f32_16x16x32_bf16(a1, b0, acc[1][0], 0, 0, 0);
        acc[1][1] = __builtin_amdgcn_mfma_f32_16x16x32_bf16(a1, b1, acc[1][1], 0, 0, 0);
    }

    float* outp = qkv + b * QO * HWs;
#pragma unroll
    for (int ti = 0; ti < 2; ++ti)
#pragma unroll
        for (int tj = 0; tj < 2; ++tj)
#pragma unroll
            for (int r = 0; r < 4; ++r) {
                const int o = o0 + oo + ti * 16 + quad * 4 + r;
                const int p = p0 + pp + tj * 16 + l15;
                outp[o * HWs + p] = acc[ti][tj][r];
            }
}

// ---------------------------------------------------------------------------
// K2: attention via exact Taylor moments. 2 slices per wave (interleaved
// independent shfl-reduce chains amortize the 6-stage latency), 8 slices
// per block, grid 192 (no tail block-wave, no converter branch).
// ---------------------------------------------------------------------------
__global__ __launch_bounds__(256)
void k_attn(const float* __restrict__ qkv, short* __restrict__ aoT) {
    __shared__ float sOutT[8][256];            // [slice-in-block][p]
    const int bk = blockIdx.x;                 // 0..191
    const int lane = threadIdx.x & 63;
    const int w = threadIdx.x >> 6;
    const int b = (bk >= 96) ? 1 : 0;
    const int o2base = bk * 8 - b * TDs;       // multiple of 8, no b straddle
    const float* base = qkv + b * QO * HWs;
    const int s0 = o2base + w * 2;             // this wave's 2 slices

    const float* kp0 = base + (TDs + s0) * HWs;
    const float* vp0 = base + (2 * TDs + s0) * HWs;
    float4 k40 = *(const float4*)(kp0 + lane * 4);
    float4 v40 = *(const float4*)(vp0 + lane * 4);
    float4 k41 = *(const float4*)(kp0 + HWs + lane * 4);
    float4 v41 = *(const float4*)(vp0 + HWs + lane * 4);

    float A[2][8] = {}, B[2][8] = {};
    {
        const float kk[2][4] = {{k40.x, k40.y, k40.z, k40.w},
                                {k41.x, k41.y, k41.z, k41.w}};
        const float vv[2][4] = {{v40.x, v40.y, v40.z, v40.w},
                                {v41.x, v41.y, v41.z, v41.w}};
#pragma unroll
        for (int sl = 0; sl < 2; ++sl)
#pragma unroll
            for (int e = 0; e < 4; ++e) {
                const float k = kk[sl][e], v = vv[sl][e];
                float p = 1.f;
#pragma unroll
                for (int m = 0; m < 8; ++m) {
                    A[sl][m] += p * v;
                    B[sl][m] += p;
                    p *= k;
                }
            }
    }
#pragma unroll
    for (int off = 1; off < 64; off <<= 1) {
#pragma unroll
        for (int sl = 0; sl < 2; ++sl)
#pragma unroll
            for (int m = 0; m < 8; ++m) {
                A[sl][m] += __shfl_xor(A[sl][m], off, 64);
                B[sl][m] += __shfl_xor(B[sl][m], off, 64);
            }
    }
    const float inv_fact[8] = {1.f, 1.f, 0.5f, 1.f / 6.f, 1.f / 24.f,
                               1.f / 120.f, 1.f / 720.f, 1.f / 5040.f};
#pragma unroll
    for (int sl = 0; sl < 2; ++sl)
#pragma unroll
        for (int m = 0; m < 8; ++m) {
            A[sl][m] *= inv_fact[m];
            B[sl][m] *= inv_fact[m];
        }

    const float* qp0 = base + s0 * HWs;
    float4 q40 = *(const float4*)(qp0 + lane * 4);
    float4 q41 = *(const float4*)(qp0 + HWs + lane * 4);
    {
        const float qq[2][4] = {{q40.x, q40.y, q40.z, q40.w},
                                {q41.x, q41.y, q41.z, q41.w}};
#pragma unroll
        for (int sl = 0; sl < 2; ++sl) {
            float4 o4;
            float ot[4];
#pragma unroll
            for (int e = 0; e < 4; ++e) {
                const float u = qq[sl][e] * 0.125f;
                float N = A[sl][7], D = B[sl][7];
#pragma unroll
                for (int m = 6; m >= 0; --m) {
                    N = fmaf(N, u, A[sl][m]);
                    D = fmaf(D, u, B[sl][m]);
                }
                ot[e] = N / D;
            }
            o4.x = ot[0]; o4.y = ot[1]; o4.z = ot[2]; o4.w = ot[3];
            *(float4*)&sOutT[w * 2 + sl][lane * 4] = o4;
        }
    }
    __syncthreads();
    const int t = threadIdx.x;
    short8 sv;
#pragma unroll
    for (int ws = 0; ws < 8; ++ws) sv[ws] = f2bf(sOutT[ws][t]);
    *(short8*)&aoT[(b * HWs + t) * TDs + o2base] = sv;
}

// ---------------------------------------------------------------------------
// K3: split-K output projection via bf16 MFMA (unchanged, proven).
// part[z][c][p] = sum_{k in slice} wout[c][k]*ao[k][p], z=b*8+ks, Kslice=96.
// ---------------------------------------------------------------------------
__global__ __launch_bounds__(256)
void k_proj(const short* __restrict__ wout_bf, const short* __restrict__ aoT,
            float* __restrict__ part) {
    __shared__ __align__(16) short sA[64 * 128];
    __shared__ __align__(16) short sB[64 * 128];
    const int tid = threadIdx.x;
    const int c0 = blockIdx.x * 64, p0 = blockIdx.y * 64;
    const int z = blockIdx.z, b = z >> 3, ks = z & 7;
    const int k0 = ks * 96;

#pragma unroll
    for (int i = 0; i < 6; ++i) {               // 1536 short4 per tensor
        const int idx = i * 256 + tid;
        const int row = idx / 24, col4 = idx - row * 24;
        const int lds = row * 128 + ((((col4 >> 1) ^ (row & 15)) << 3)) + ((col4 & 1) << 2);
        short4 a = *(const short4*)&wout_bf[(c0 + row) * TDs + k0 + col4 * 4];
        *(short4*)&sA[lds] = a;
        short4 bb = *(const short4*)&aoT[(b * HWs + p0 + row) * TDs + k0 + col4 * 4];
        *(short4*)&sB[lds] = bb;
    }
    __syncthreads();

    const int w = tid >> 6, lane = tid & 63;
    const int quad = lane >> 4, l15 = lane & 15;
    const int cc = (w & 1) * 32, pp = (w >> 1) * 32;
    f32x4 acc[2][2] = {};

#pragma unroll
    for (int step = 0; step < 3; ++step) {
        const int chunk = step * 4 + quad;
        const int ra0 = cc + l15, ra1 = cc + 16 + l15;
        const int rb0 = pp + l15, rb1 = pp + 16 + l15;
        short8 a0 = *(const short8*)&sA[ra0 * 128 + ((chunk ^ (ra0 & 15)) << 3)];
        short8 a1 = *(const short8*)&sA[ra1 * 128 + ((chunk ^ (ra1 & 15)) << 3)];
        short8 b0 = *(const short8*)&sB[rb0 * 128 + ((chunk ^ (rb0 & 15)) << 3)];
        short8 b1 = *(const short8*)&sB[rb1 * 128 + ((chunk ^ (rb1 & 15)) << 3)];
        acc[0][0] = __builtin_amdgcn_mfma_f32_16x16x32_bf16(a0, b0, acc[0][0], 0, 0, 0);
        acc[0][1] = __builtin_amdgcn_mfma_f32_16x16x32_bf16(a0, b1, acc[0][1], 0, 0, 0);
        acc[1][0] = __builtin_amdgcn_mfma_f32_16x16x32_bf16(a1, b0, acc[1][0], 0, 0, 0);
        acc[1][1] = __builtin_amdgcn_mfma_f32_16x16x32_bf16(a1, b1, acc[1][1], 0, 0, 0);
    }

    float* op = part + z * (CC * HWs);
#pragma unroll
    for (int ti = 0; ti < 2; ++ti)
#pragma unroll
        for (int tj = 0; tj < 2; ++tj)
#pragma unroll
            for (int r = 0; r < 4; ++r) {
                const int c = c0 + cc + ti * 16 + quad * 4 + r;
                const int p = p0 + pp + tj * 16 + l15;
                op[c * HWs + p] = acc[ti][tj][r];
            }
}

// ---------------------------------------------------------------------------
// K4: y = x + sum_ks part ; LayerNorm over p per (b,c); write out.
// One 64-thread wave per (b,c) row, float4 loads, pure shfl reduction.
// ---------------------------------------------------------------------------
__global__ __launch_bounds__(64)
void k_ln(const float* __restrict__ x, const float* __restrict__ part,
          float* __restrict__ out) {
    const int lane = threadIdx.x;
    const int bc = blockIdx.x;         // b*256 + c
    const int b = bc >> 8, c = bc & 255;

    float4 y = *(const float4*)(x + bc * HWs + lane * 4);
#pragma unroll
    for (int ks = 0; ks < 8; ++ks) {
        float4 pv = *(const float4*)(part + (((b * 8 + ks) * CC + c) * HWs) + lane * 4);
        y.x += pv.x; y.y += pv.y; y.z += pv.z; y.w += pv.w;
    }

    float s  = (y.x + y.y) + (y.z + y.w);
    float ss = (y.x * y.x + y.y * y.y) + (y.z * y.z + y.w * y.w);
#pragma unroll
    for (int off = 1; off < 64; off <<= 1) {
        s  += __shfl_xor(s, off, 64);
        ss += __shfl_xor(ss, off, 64);
    }
    const float mu  = s * (1.f / 256.f);
    const float var = ss * (1.f / 256.f) - mu * mu;
    const float inv = rsqrtf(var + 1e-5f);
    float4 o;
    o.x = (y.x - mu) * inv;
    o.y = (y.y - mu) * inv;
    o.z = (y.z - mu) * inv;
    o.w = (y.w - mu) * inv;
    *(float4*)(out + bc * HWs + lane * 4) = o;
}

// ---------------------------------------------------------------------------
extern "C" void kernel_launch(void* const* d_in, const int* in_sizes, int n_in,
                              void* d_out, int out_size, void* d_ws, size_t ws_size,
                              hipStream_t stream) {
    const float* x    = (const float*)d_in[0];
    const float* wqkv = (const float*)d_in[1];
    const float* wout = (const float*)d_in[2];
    // d_in[3] = b_out: zeros, and per-row constants cancel in LayerNorm.

    char* ws = (char*)d_ws;
    float* qkv    = (float*)(ws);                    // 2*2304*256 f32 = 4,718,592 B
    short* aoT    = (short*)(ws + 4718592);          // 2*256*768 bf16 =  786,432 B
    short* woutb  = (short*)(ws + 5505024);          // 256*768  bf16 =  393,216 B
    float* part   = (float*)(ws + 5898240);          // 16*256*256 f32 = 4,194,304 B
    float* out    = (float*)d_out;

    k_qkv <<<dim3(40, 4, 2), 256, 0, stream>>>(wqkv, x, qkv, wout, woutb);
    k_attn<<<dim3(192),      256, 0, stream>>>(qkv, aoT);
    k_proj<<<dim3(4, 4, 16), 256, 0, stream>>>(woutb, aoT, part);
    k_ln  <<<dim3(512),       64, 0, stream>>>(x, part, out);
}